// Round 1
// baseline (734.818 us; speedup 1.0000x reference)
//
#include <hip/hip_runtime.h>

// Problem constants
#define BQ 8
#define CQ 16
#define LQ 2048
#define NQ 2048
#define NPS 128      // nperseg
#define STEPQ 64     // step (50% overlap)
#define SQ 31        // segments per series
#define FQ 65        // rfft bins
#define KQ 32        // nref
#define EPSQ 1e-12f

// ---- workspace layout (bytes) ----
// tables (floats): [0,128) win | [128,416) t16 (float2[144]) | [416,1456) w128 (float2[520])
#define TAB_FLOATS 1456
#define XSPEC_OFF  6144ull                      // float2 [B][F][S][C] = 257920 float2
#define PXX_OFF    2069504ull                   // float [B][C][F] = 8320 floats
#define SCORES_OFF 2102784ull                   // float [B][C][N] = 262144 floats
#define TOPK_OFF   3151360ull                   // int [B][C][K] = 8192 ints

// ---- shared memory layout (float offsets) ----
#define XW_LD     136                            // padded leading dim: 136%32==8 -> 2-way banks (free)
#define OFF_WIN   0                              // 128
#define OFF_T16   128                            // float2[144] = 288 floats
#define OFF_W128  416                            // float2[520] = 1040 floats
#define OFF_Y     1456                           // float2[2015] = 4030 floats
#define OFF_PYY   5486                           // 65
#define OFF_RED   5551                           // 256
#define OFF_MEAN  5807                           // 31
#define OFF_XW    5838                           // 31*136 = 4216
#define OFF_AREA2 10054                          // max(row 2048 + part 248, G float2[2232]=4464) = 4464
#define SMEM_FLOATS 14518                        // ~58 KB -> 2 blocks/CU

__global__ void k_tables(float* __restrict__ gtab) {
    const int tid = threadIdx.x;
    const double PI2 = 6.283185307179586476925286766559;
    if (tid < 128) {
        gtab[tid] = (float)(0.5 - 0.5 * cos(PI2 * (double)tid / 128.0));
    }
    if (tid < 144) {
        int m = tid >> 4, t2 = tid & 15;
        double a = PI2 * (double)(m * t2) / 16.0;
        gtab[128 + 2 * tid]     = (float)cos(a);
        gtab[128 + 2 * tid + 1] = (float)(-sin(a));
    }
    for (int j = tid; j < 520; j += 256) {
        int t1 = j / 65, k = j % 65;
        double a = PI2 * (double)(t1 * k) / 128.0;
        gtab[416 + 2 * j]     = (float)cos(a);
        gtab[416 + 2 * j + 1] = (float)(-sin(a));
    }
}

// Compute Welch spectra of one length-2048 row into smem Y (float2 [31][65]).
// Uses the 128 = 8x16 DFT factorization with real-input symmetry on the inner stage.
__device__ __forceinline__ void welch_spectra(const float* __restrict__ grow,
                                              const float* __restrict__ gtab,
                                              float* smem) {
    const int tid = threadIdx.x;
    float*  s_win  = smem + OFF_WIN;
    float2* s_t16  = (float2*)(smem + OFF_T16);
    float2* s_w    = (float2*)(smem + OFF_W128);
    float2* s_y    = (float2*)(smem + OFF_Y);
    float*  s_mean = smem + OFF_MEAN;
    float*  s_xw   = smem + OFF_XW;
    float*  s_row  = smem + OFF_AREA2;           // phase 1 use of area2
    float*  s_part = smem + OFF_AREA2 + 2048;
    float2* s_g2   = (float2*)(smem + OFF_AREA2); // phase 2 use of area2 (after row is dead)

    // load tables (contiguous in ws) + input row
    for (int i = tid; i < TAB_FLOATS; i += 256) smem[i] = gtab[i];
    for (int i = tid; i < LQ; i += 256) s_row[i] = grow[i];
    __syncthreads();

    // per-segment mean (detrend='constant'): 8 partials of 16 per segment
    if (tid < SQ * 8) {
        int s = tid >> 3, l = tid & 7;
        const float* p = s_row + s * STEPQ + l * 16;
        float a = 0.f;
#pragma unroll
        for (int j = 0; j < 16; ++j) a += p[j];
        s_part[tid] = a;
    }
    __syncthreads();
    if (tid < SQ) {
        float a = 0.f;
#pragma unroll
        for (int j = 0; j < 8; ++j) a += s_part[tid * 8 + j];
        s_mean[tid] = a * (1.0f / 128.0f);
    }
    __syncthreads();

    // windowed, detrended frames: xw[s][t] = (x[s*64+t]-mean[s])*win[t]
    for (int i = tid; i < SQ * NPS; i += 256) {
        int s = i >> 7, t = i & 127;
        s_xw[s * XW_LD + t] = (s_row[s * STEPQ + t] - s_mean[s]) * s_win[t];
    }
    __syncthreads();

    // stage 1: G[s][t1][m] = sum_{t2<16} xw[s][t1+8*t2] * e^{-2pi i t2 m/16}, m=0..8
    if (tid < SQ * 8) {
        int s = tid >> 3, t1 = tid & 7;
        float xr[16];
#pragma unroll
        for (int t2 = 0; t2 < 16; ++t2) xr[t2] = s_xw[s * XW_LD + t1 + 8 * t2];
#pragma unroll
        for (int m = 0; m < 9; ++m) {
            float gr = 0.f, gi = 0.f;
#pragma unroll
            for (int t2 = 0; t2 < 16; ++t2) {
                float2 tt = s_t16[m * 16 + t2];   // wave-broadcast
                gr += xr[t2] * tt.x;
                gi += xr[t2] * tt.y;
            }
            s_g2[tid * 9 + m] = make_float2(gr, gi);
        }
    }
    __syncthreads();

    // stage 2: Y[s][k] = sum_{t1<8} e^{-2pi i t1 k/128} * G[s][t1][k mod 16]
    for (int i = tid; i < SQ * FQ; i += 256) {
        int k = i % 65, s = i / 65;
        int m = k & 15;
        int mm = (m <= 8) ? m : 16 - m;
        float sg = (m <= 8) ? 1.0f : -1.0f;      // conj for m>8 (real input symmetry)
        float yr = 0.f, yi = 0.f;
        int st = s * 8;
#pragma unroll
        for (int t1 = 0; t1 < 8; ++t1) {
            float2 g = s_g2[(st + t1) * 9 + mm];
            float gi2 = g.y * sg;
            float2 w = s_w[t1 * 65 + k];
            yr += w.x * g.x - w.y * gi2;
            yi += w.x * gi2 + w.y * g.x;
        }
        s_y[i] = make_float2(yr, yi);
    }
    __syncthreads();
}

// Target spectra: one block per (b,c). Writes Xspec [B][F][S][C] (float2) and Pxx [B][C][F].
__global__ __launch_bounds__(256) void k_xspec(const float* __restrict__ tgt,
                                               const float* __restrict__ gtab,
                                               float2* __restrict__ xspec,
                                               float* __restrict__ pxx) {
    __shared__ float smem[SMEM_FLOATS];
    const int blk = blockIdx.x;            // b*16 + c
    const int b = blk >> 4, c = blk & 15;
    welch_spectra(tgt + (size_t)blk * LQ, gtab, smem);
    const float2* s_y = (const float2*)(smem + OFF_Y);
    const int tid = threadIdx.x;
    for (int i = tid; i < SQ * FQ; i += 256) {
        int k = i % 65, s = i / 65;
        xspec[((size_t)b * FQ + k) * (SQ * CQ) + s * CQ + c] = s_y[i];
    }
    if (tid < FQ) {
        float a = 0.f;
        for (int s = 0; s < SQ; ++s) {
            float2 y = s_y[s * FQ + tid];
            a += y.x * y.x + y.y * y.y;
        }
        pxx[(size_t)blk * FQ + tid] = a * (1.0f / (float)SQ);
    }
}

// Score: one block per (b,n). Computes Y spectra, Pyy, then coherence vs all 16 channels.
__global__ __launch_bounds__(256) void k_score(const float* __restrict__ db,
                                               const float* __restrict__ gtab,
                                               const float2* __restrict__ xspec,
                                               const float* __restrict__ pxx,
                                               float* __restrict__ scores) {
    __shared__ float smem[SMEM_FLOATS];
    const int blk = blockIdx.x;            // b*2048 + n
    const int b = blk >> 11, n = blk & 2047;
    welch_spectra(db + (size_t)blk * LQ, gtab, smem);
    const float2* s_y = (const float2*)(smem + OFF_Y);
    float* s_pyy = smem + OFF_PYY;
    float* s_red = smem + OFF_RED;
    const int tid = threadIdx.x;

    if (tid < FQ) {
        float a = 0.f;
        for (int s = 0; s < SQ; ++s) {
            float2 y = s_y[s * FQ + tid];
            a += y.x * y.x + y.y * y.y;
        }
        s_pyy[tid] = a * (1.0f / (float)SQ);
    }
    __syncthreads();

    const int c = tid & 15, g = tid >> 4;
    const float2* xb = xspec + (size_t)b * (FQ * SQ * CQ) + c;
    const float*  px = pxx + ((size_t)b * CQ + c) * FQ;
    float acc = 0.f;
    for (int f = g; f < FQ; f += 16) {
        const float2* xp = xb + (size_t)f * (SQ * CQ);
        float pr = 0.f, pi = 0.f;
#pragma unroll
        for (int s = 0; s < SQ; ++s) {
            float2 xv = xp[s * CQ];             // coalesced 128B per 16-lane group
            float2 yv = s_y[s * FQ + f];        // 16-lane broadcast
            pr += xv.x * yv.x + xv.y * yv.y;    // X * conj(Y)
            pi += xv.y * yv.x - xv.x * yv.y;
        }
        float num = (pr * pr + pi * pi) * (1.0f / ((float)SQ * (float)SQ));
        float den = px[f] * s_pyy[f] + EPSQ;
        acc += num / den;
    }
    s_red[g * 16 + c] = acc;
    __syncthreads();
    if (tid < 16) {
        float a = 0.f;
#pragma unroll
        for (int gg = 0; gg < 16; ++gg) a += s_red[gg * 16 + tid];
        scores[((size_t)b * CQ + tid) * NQ + n] = a * (1.0f / (float)FQ);
    }
}

// Top-32 per (b,c) row, jax.lax.top_k semantics (descending, ties -> smallest index).
__global__ __launch_bounds__(256) void k_topk(const float* __restrict__ scores,
                                              int* __restrict__ topk) {
    __shared__ float sv[NQ];
    __shared__ float rv[256];
    __shared__ int   ri[256];
    const int blk = blockIdx.x, tid = threadIdx.x;
    const float* row = scores + (size_t)blk * NQ;
    for (int i = tid; i < NQ; i += 256) sv[i] = row[i];
    __syncthreads();
    for (int k = 0; k < KQ; ++k) {
        float best = -3.402823466e38f;
        int bi = 0x7fffffff;
        for (int j = tid; j < NQ; j += 256) {
            float v = sv[j];
            if (v > best) { best = v; bi = j; }   // ascending j: strict > keeps smallest idx
        }
        rv[tid] = best; ri[tid] = bi;
        __syncthreads();
        for (int off = 128; off > 0; off >>= 1) {
            if (tid < off) {
                float v2 = rv[tid + off]; int i2 = ri[tid + off];
                if (v2 > rv[tid] || (v2 == rv[tid] && i2 < ri[tid])) { rv[tid] = v2; ri[tid] = i2; }
            }
            __syncthreads();
        }
        if (tid == 0) { topk[blk * KQ + k] = ri[0]; sv[ri[0]] = -3.402823466e38f; }
        __syncthreads();
    }
}

// Gather: one block per output row (b, c*32+k) -> copy DB row (2048 floats) via float4.
__global__ __launch_bounds__(256) void k_gather(const float* __restrict__ db,
                                                const int* __restrict__ topk,
                                                float* __restrict__ out) {
    const int row = blockIdx.x;               // b*512 + c*32 + k
    const int b = row >> 9;
    const int idx = topk[row];
    const float4* src = (const float4*)(db + ((size_t)(b * NQ + idx)) * LQ);
    float4* dst = (float4*)(out + (size_t)row * LQ);
    const int tid = threadIdx.x;
    dst[tid] = src[tid];
    dst[tid + 256] = src[tid + 256];
}

extern "C" void kernel_launch(void* const* d_in, const int* in_sizes, int n_in,
                              void* d_out, int out_size, void* d_ws, size_t ws_size,
                              hipStream_t stream) {
    const float* tgt = (const float*)d_in[0];   // [8,16,2048]
    const float* db  = (const float*)d_in[1];   // [8,2048,2048]
    float* out = (float*)d_out;                 // [8,512,2048]
    char* ws = (char*)d_ws;

    float*  gtab   = (float*)(ws);
    float2* xspec  = (float2*)(ws + XSPEC_OFF);
    float*  pxx    = (float*)(ws + PXX_OFF);
    float*  scores = (float*)(ws + SCORES_OFF);
    int*    topk   = (int*)(ws + TOPK_OFF);

    hipLaunchKernelGGL(k_tables, dim3(1),            dim3(256), 0, stream, gtab);
    hipLaunchKernelGGL(k_xspec,  dim3(BQ * CQ),      dim3(256), 0, stream, tgt, gtab, xspec, pxx);
    hipLaunchKernelGGL(k_score,  dim3(BQ * NQ),      dim3(256), 0, stream, db, gtab, xspec, pxx, scores);
    hipLaunchKernelGGL(k_topk,   dim3(BQ * CQ),      dim3(256), 0, stream, scores, topk);
    hipLaunchKernelGGL(k_gather, dim3(BQ * CQ * KQ), dim3(256), 0, stream, db, topk, out);
}